// Round 1
// baseline (205.917 us; speedup 1.0000x reference)
//
#include <hip/hip_runtime.h>
#include <hip/hip_bf16.h>

// AdaDConv: B=8, C=256, H=W=128, K=3, S=2 -> oh=ow=64, k2=9
// Stages:
//   prep : fold BN into conv weights, transpose to [c][84] (padded), bias[9]
//   gap  : x -> gap (8,256)
//   chnet: gap -> ch (8,256)   (relu(gap@w1^T)@w2^T)
//   conv : x -> wlog (8,64,64,12)  (9 taps + 3 pad), BN folded
//   final: softmax over taps * reflect-padded patches -> out (8,256,64,64)

#define EPS 1e-5f

__global__ __launch_bounds__(256) void prep_kernel(
    const float* __restrict__ wconv, const float* __restrict__ gamma,
    const float* __restrict__ beta, const float* __restrict__ mean,
    const float* __restrict__ var, float* __restrict__ wt,
    float* __restrict__ bias) {
  const int c = threadIdx.x;  // 0..255
  #pragma unroll
  for (int t = 0; t < 9; ++t) {
    float sc = gamma[t] * rsqrtf(var[t] + EPS);
    #pragma unroll
    for (int p = 0; p < 9; ++p)
      wt[c * 84 + t * 9 + p] = wconv[((size_t)t * 256 + c) * 9 + p] * sc;
  }
  wt[c * 84 + 81] = 0.f;
  wt[c * 84 + 82] = 0.f;
  wt[c * 84 + 83] = 0.f;
  if (c < 9) bias[c] = beta[c] - mean[c] * gamma[c] * rsqrtf(var[c] + EPS);
  else if (c < 16) bias[c] = 0.f;
}

__global__ __launch_bounds__(256) void gap_kernel(const float* __restrict__ x,
                                                  float* __restrict__ gap) {
  const int bc = blockIdx.x;  // 0..2047
  const float4* p4 = (const float4*)(x + (size_t)bc * 16384);
  float s = 0.f;
  for (int k = threadIdx.x; k < 4096; k += 256) {
    float4 v = p4[k];
    s += (v.x + v.y) + (v.z + v.w);
  }
  #pragma unroll
  for (int off = 32; off > 0; off >>= 1) s += __shfl_down(s, off, 64);
  __shared__ float red[4];
  if ((threadIdx.x & 63) == 0) red[threadIdx.x >> 6] = s;
  __syncthreads();
  if (threadIdx.x == 0)
    gap[bc] = (red[0] + red[1] + red[2] + red[3]) * (1.f / 16384.f);
}

__global__ __launch_bounds__(256) void chnet_kernel(
    const float* __restrict__ gap, const float* __restrict__ w1,
    const float* __restrict__ w2, float* __restrict__ ch) {
  const int b = blockIdx.x;  // 0..7
  __shared__ float g[256];
  __shared__ float h[64];
  const int t = threadIdx.x;
  g[t] = gap[b * 256 + t];
  __syncthreads();
  if (t < 64) {
    float s = 0.f;
    const float* w = w1 + t * 256;
    for (int c = 0; c < 256; ++c) s += g[c] * w[c];
    h[t] = fmaxf(s, 0.f);
  }
  __syncthreads();
  float s = 0.f;
  const float* w = w2 + t * 64;
  #pragma unroll 4
  for (int j = 0; j < 64; ++j) s += h[j] * w[j];
  ch[b * 256 + t] = s;
}

__global__ __launch_bounds__(256) void conv_kernel(
    const float* __restrict__ x, const float* __restrict__ wt,
    const float* __restrict__ bias, float* __restrict__ wlog) {
  const int jl = threadIdx.x & 31;
  const int cq = threadIdx.x >> 5;  // 0..7
  const int j = blockIdx.x * 32 + jl;
  const int i = blockIdx.y;
  const int b = blockIdx.z;
  const int h0 = 2 * i - 1, w0 = 2 * j - 1;

  float acc[9];
  #pragma unroll
  for (int t = 0; t < 9; ++t) acc[t] = 0.f;

  const float* xb = x + ((size_t)b * 256 + cq * 32) * 16384;
  const float* wc = wt + (size_t)(cq * 32) * 84;

  for (int c = 0; c < 32; ++c, xb += 16384, wc += 84) {
    float xv[9];
    #pragma unroll
    for (int ki = 0; ki < 3; ++ki) {
      int hh = h0 + ki;
      bool hok = ((unsigned)hh < 128u);
      #pragma unroll
      for (int kj = 0; kj < 3; ++kj) {
        int ww = w0 + kj;
        bool ok = hok && ((unsigned)ww < 128u);
        xv[ki * 3 + kj] = ok ? xb[hh * 128 + ww] : 0.f;
      }
    }
    const float4* wp = (const float4*)wc;
    #pragma unroll
    for (int q = 0; q < 21; ++q) {
      float4 wv = wp[q];
      #pragma unroll
      for (int e = 0; e < 4; ++e) {
        int idx = q * 4 + e;
        if (idx < 81) {
          float wval = (e == 0) ? wv.x : (e == 1) ? wv.y : (e == 2) ? wv.z : wv.w;
          acc[idx / 9] += xv[idx - (idx / 9) * 9] * wval;
        }
      }
    }
  }

  __shared__ float red[8][32][9];
  #pragma unroll
  for (int t = 0; t < 9; ++t) red[cq][jl][t] = acc[t];
  __syncthreads();

  // reduce across cq: thread tid -> (jj = tid&31, tt = tid>>5 in 0..7)
  const int jj = threadIdx.x & 31;
  const int tt = threadIdx.x >> 5;
  const size_t pos = ((size_t)b * 64 + i) * 64 + (blockIdx.x * 32 + jj);
  {
    float s = 0.f;
    #pragma unroll
    for (int q = 0; q < 8; ++q) s += red[q][jj][tt];
    wlog[pos * 12 + tt] = s + bias[tt];
  }
  if (tt == 0) {
    float s = 0.f;
    #pragma unroll
    for (int q = 0; q < 8; ++q) s += red[q][jj][8];
    wlog[pos * 12 + 8] = s + bias[8];
  }
  if (tt >= 1 && tt <= 3) wlog[pos * 12 + 8 + tt] = 0.f;  // pad slots 9..11
}

__global__ __launch_bounds__(256) void final_kernel(
    const float* __restrict__ x, const float* __restrict__ wlog,
    const float* __restrict__ ch, float* __restrict__ out) {
  const int j = threadIdx.x & 63;
  const int il = threadIdx.x >> 6;  // 0..3
  const int i = blockIdx.x * 4 + il;
  const int c = blockIdx.y;
  const int b = blockIdx.z;
  const float chv = ch[b * 256 + c];

  const size_t pos = ((size_t)b * 64 + i) * 64 + j;
  const float4* wp = (const float4*)(wlog + pos * 12);
  float4 wa = wp[0], wb = wp[1], wcv = wp[2];
  float lg[9] = {wa.x, wa.y, wa.z, wa.w, wb.x, wb.y, wb.z, wb.w, wcv.x};

  float m = -3.4e38f;
  #pragma unroll
  for (int t = 0; t < 9; ++t) {
    lg[t] *= chv;
    m = fmaxf(m, lg[t]);
  }
  float e[9], s = 0.f;
  #pragma unroll
  for (int t = 0; t < 9; ++t) {
    e[t] = __expf(lg[t] - m);
    s += e[t];
  }
  const float inv = 1.f / s;

  const float* xp = x + ((size_t)b * 256 + c) * 16384;
  const int h0 = 2 * i - 1, w0c = 2 * j - 1;
  float acc = 0.f;
  #pragma unroll
  for (int ki = 0; ki < 3; ++ki) {
    int hh = h0 + ki;
    hh = hh < 0 ? -hh : (hh > 127 ? 254 - hh : hh);
    #pragma unroll
    for (int kj = 0; kj < 3; ++kj) {
      int ww = w0c + kj;
      ww = ww < 0 ? -ww : (ww > 127 ? 254 - ww : ww);
      acc += e[ki * 3 + kj] * xp[hh * 128 + ww];
    }
  }
  out[(size_t)(b * 256 + c) * 4096 + i * 64 + j] = acc * inv;
}

extern "C" void kernel_launch(void* const* d_in, const int* in_sizes, int n_in,
                              void* d_out, int out_size, void* d_ws,
                              size_t ws_size, hipStream_t stream) {
  const float* x = (const float*)d_in[0];
  const float* w_conv = (const float*)d_in[1];
  const float* bn_gamma = (const float*)d_in[2];
  const float* bn_beta = (const float*)d_in[3];
  const float* bn_mean = (const float*)d_in[4];
  const float* bn_var = (const float*)d_in[5];
  const float* ch_w1 = (const float*)d_in[6];
  const float* ch_w2 = (const float*)d_in[7];
  float* out = (float*)d_out;

  float* wsf = (float*)d_ws;
  float* gap = wsf;           // 2048
  float* ch = wsf + 2048;     // 2048
  float* bias = wsf + 4096;   // 16
  float* wt = wsf + 4112;     // 256*84 = 21504
  float* wlog = wsf + 25616;  // 8*64*64*12 = 393216  (16B-aligned offset)

  prep_kernel<<<1, 256, 0, stream>>>(w_conv, bn_gamma, bn_beta, bn_mean,
                                     bn_var, wt, bias);
  gap_kernel<<<2048, 256, 0, stream>>>(x, gap);
  chnet_kernel<<<8, 256, 0, stream>>>(gap, ch_w1, ch_w2, ch);
  conv_kernel<<<dim3(2, 64, 8), 256, 0, stream>>>(x, wt, bias, wlog);
  final_kernel<<<dim3(16, 256, 8), 256, 0, stream>>>(x, wlog, ch, out);
}

// Round 2
// 162.257 us; speedup vs baseline: 1.2691x; 1.2691x over previous
//
#include <hip/hip_runtime.h>
#include <hip/hip_bf16.h>

// AdaDConv: B=8, C=256, H=W=128, K=3, S=2 -> oh=ow=64, k2=9
// Stages:
//   prep : fold BN into conv weights -> wt[c][84], bias[9]
//   init : wlog[pos][12] <- bias (taps 0..8), 0 (pad 9..11)
//   gap  : x -> gap (8,256)
//   chnet: gap -> ch (8,256)
//   conv : x -> wlog via scalar-weight FMA + atomicAdd partials
//   final: softmax over taps * reflect-padded patches -> out

#define EPS 1e-5f
#define CH_SPLIT 2

__global__ __launch_bounds__(256) void prep_kernel(
    const float* __restrict__ wconv, const float* __restrict__ gamma,
    const float* __restrict__ beta, const float* __restrict__ mean,
    const float* __restrict__ var, float* __restrict__ wt,
    float* __restrict__ bias) {
  const int c = threadIdx.x;  // 0..255
  #pragma unroll
  for (int t = 0; t < 9; ++t) {
    float sc = gamma[t] * rsqrtf(var[t] + EPS);
    #pragma unroll
    for (int p = 0; p < 9; ++p)
      wt[c * 84 + t * 9 + p] = wconv[((size_t)t * 256 + c) * 9 + p] * sc;
  }
  wt[c * 84 + 81] = 0.f;
  wt[c * 84 + 82] = 0.f;
  wt[c * 84 + 83] = 0.f;
  if (c < 9) bias[c] = beta[c] - mean[c] * gamma[c] * rsqrtf(var[c] + EPS);
  else if (c < 16) bias[c] = 0.f;
}

// wlog[pos*12 + t] = bias[t] for t<9 else 0.  393216 floats total.
__global__ __launch_bounds__(256) void init_wlog_kernel(
    const float* __restrict__ bias, float* __restrict__ wlog) {
  const int idx = blockIdx.x * 256 + threadIdx.x;
  const int t = idx % 12;
  wlog[idx] = (t < 9) ? bias[t] : 0.f;
}

__global__ __launch_bounds__(256) void gap_kernel(const float* __restrict__ x,
                                                  float* __restrict__ gap) {
  const int bc = blockIdx.x;  // 0..2047
  const float4* p4 = (const float4*)(x + (size_t)bc * 16384);
  float s = 0.f;
  for (int k = threadIdx.x; k < 4096; k += 256) {
    float4 v = p4[k];
    s += (v.x + v.y) + (v.z + v.w);
  }
  #pragma unroll
  for (int off = 32; off > 0; off >>= 1) s += __shfl_down(s, off, 64);
  __shared__ float red[4];
  if ((threadIdx.x & 63) == 0) red[threadIdx.x >> 6] = s;
  __syncthreads();
  if (threadIdx.x == 0)
    gap[bc] = (red[0] + red[1] + red[2] + red[3]) * (1.f / 16384.f);
}

__global__ __launch_bounds__(256) void chnet_kernel(
    const float* __restrict__ gap, const float* __restrict__ w1,
    const float* __restrict__ w2, float* __restrict__ ch) {
  const int b = blockIdx.x;  // 0..7
  __shared__ float g[256];
  __shared__ float h[64];
  const int t = threadIdx.x;
  g[t] = gap[b * 256 + t];
  __syncthreads();
  if (t < 64) {
    float s = 0.f;
    const float* w = w1 + t * 256;
    for (int c = 0; c < 256; ++c) s += g[c] * w[c];
    h[t] = fmaxf(s, 0.f);
  }
  __syncthreads();
  float s = 0.f;
  const float* w = w2 + t * 64;
  #pragma unroll 4
  for (int j = 0; j < 64; ++j) s += h[j] * w[j];
  ch[b * 256 + t] = s;
}

// Block: 256 threads = 4 waves. Wave wv handles channels
// [(z*4+wv)*32, +32) for output row i of batch b, lanes = 64 j positions.
// Weights via scalar (SMEM) loads; x via coalesced float2 + shfl_up.
__global__ __launch_bounds__(256) void conv_kernel(
    const float* __restrict__ x, const float* __restrict__ wt,
    float* __restrict__ wlog) {
  const int j = threadIdx.x & 63;    // lane = output col
  const int wv = threadIdx.x >> 6;   // wave id 0..3
  const int i = blockIdx.x;          // output row
  const int b = blockIdx.y;
  const int z = blockIdx.z;          // channel split 0..CH_SPLIT-1
  const int cbase = __builtin_amdgcn_readfirstlane((z * 4 + wv) * 32);

  float acc[9];
  #pragma unroll
  for (int t = 0; t < 9; ++t) acc[t] = 0.f;

  const float* xb = x + ((size_t)b * 256 + cbase) * 16384;
  const float* wcb = wt + (size_t)cbase * 84;
  const int h0 = 2 * i - 1;

  for (int c = 0; c < 32; ++c, xb += 16384, wcb += 84) {
    float xv[9];
    #pragma unroll
    for (int ki = 0; ki < 3; ++ki) {
      const int hh = h0 + ki;  // wave-uniform
      float2 v;
      if ((unsigned)hh < 128u)
        v = *(const float2*)(xb + hh * 128 + 2 * j);
      else
        v = make_float2(0.f, 0.f);
      float left = __shfl_up(v.y, 1, 64);
      xv[ki * 3 + 0] = (j == 0) ? 0.f : left;  // col 2j-1 (zero-pad at -1)
      xv[ki * 3 + 1] = v.x;                    // col 2j
      xv[ki * 3 + 2] = v.y;                    // col 2j+1
    }
    #pragma unroll
    for (int t = 0; t < 9; ++t) {
      #pragma unroll
      for (int p = 0; p < 9; ++p)
        acc[t] = fmaf(xv[p], wcb[t * 9 + p], acc[t]);
    }
  }

  __shared__ float red[4][64][9];
  #pragma unroll
  for (int t = 0; t < 9; ++t) red[wv][j][t] = acc[t];
  __syncthreads();

  const size_t rowpos = ((size_t)b * 64 + i) * 64;
  for (int idx = threadIdx.x; idx < 576; idx += 256) {
    const int jj = idx / 9, tt = idx - jj * 9;
    float s = red[0][jj][tt] + red[1][jj][tt] + red[2][jj][tt] + red[3][jj][tt];
    atomicAdd(&wlog[(rowpos + jj) * 12 + tt], s);
  }
}

__global__ __launch_bounds__(256) void final_kernel(
    const float* __restrict__ x, const float* __restrict__ wlog,
    const float* __restrict__ ch, float* __restrict__ out) {
  const int j = threadIdx.x & 63;
  const int il = threadIdx.x >> 6;  // 0..3
  const int i = blockIdx.x * 4 + il;
  const int c = blockIdx.y;
  const int b = blockIdx.z;
  const float chv = ch[b * 256 + c];

  const size_t pos = ((size_t)b * 64 + i) * 64 + j;
  const float4* wp = (const float4*)(wlog + pos * 12);
  float4 wa = wp[0], wb = wp[1], wcv = wp[2];
  float lg[9] = {wa.x, wa.y, wa.z, wa.w, wb.x, wb.y, wb.z, wb.w, wcv.x};

  float m = -3.4e38f;
  #pragma unroll
  for (int t = 0; t < 9; ++t) {
    lg[t] *= chv;
    m = fmaxf(m, lg[t]);
  }
  float e[9], s = 0.f;
  #pragma unroll
  for (int t = 0; t < 9; ++t) {
    e[t] = __expf(lg[t] - m);
    s += e[t];
  }
  const float inv = 1.f / s;

  const float* xp = x + ((size_t)b * 256 + c) * 16384;
  const int h0 = 2 * i - 1, w0c = 2 * j - 1;
  float acc = 0.f;
  #pragma unroll
  for (int ki = 0; ki < 3; ++ki) {
    int hh = h0 + ki;
    hh = hh < 0 ? -hh : (hh > 127 ? 254 - hh : hh);
    #pragma unroll
    for (int kj = 0; kj < 3; ++kj) {
      int ww = w0c + kj;
      ww = ww < 0 ? -ww : (ww > 127 ? 254 - ww : ww);
      acc += e[ki * 3 + kj] * xp[hh * 128 + ww];
    }
  }
  out[(size_t)(b * 256 + c) * 4096 + i * 64 + j] = acc * inv;
}

extern "C" void kernel_launch(void* const* d_in, const int* in_sizes, int n_in,
                              void* d_out, int out_size, void* d_ws,
                              size_t ws_size, hipStream_t stream) {
  const float* x = (const float*)d_in[0];
  const float* w_conv = (const float*)d_in[1];
  const float* bn_gamma = (const float*)d_in[2];
  const float* bn_beta = (const float*)d_in[3];
  const float* bn_mean = (const float*)d_in[4];
  const float* bn_var = (const float*)d_in[5];
  const float* ch_w1 = (const float*)d_in[6];
  const float* ch_w2 = (const float*)d_in[7];
  float* out = (float*)d_out;

  float* wsf = (float*)d_ws;
  float* gap = wsf;           // 2048
  float* ch = wsf + 2048;     // 2048
  float* bias = wsf + 4096;   // 16
  float* wt = wsf + 4112;     // 256*84 = 21504
  float* wlog = wsf + 25616;  // 8*64*64*12 = 393216  (16B-aligned offset)

  prep_kernel<<<1, 256, 0, stream>>>(w_conv, bn_gamma, bn_beta, bn_mean,
                                     bn_var, wt, bias);
  init_wlog_kernel<<<1536, 256, 0, stream>>>(bias, wlog);
  gap_kernel<<<2048, 256, 0, stream>>>(x, gap);
  chnet_kernel<<<8, 256, 0, stream>>>(gap, ch_w1, ch_w2, ch);
  conv_kernel<<<dim3(64, 8, CH_SPLIT), 256, 0, stream>>>(x, wt, wlog);
  final_kernel<<<dim3(16, 256, 8), 256, 0, stream>>>(x, wlog, ch, out);
}

// Round 3
// 94.253 us; speedup vs baseline: 2.1847x; 1.7215x over previous
//
#include <hip/hip_runtime.h>
#include <hip/hip_bf16.h>

// AdaDConv: B=8, C=256, H=W=128, K=3, S=2 -> oh=ow=64, k2=9
//   prep : fold BN into conv weights -> wt[c][84], bias[9]; zero gap
//   init : wlog[pos][12] <- bias (taps 0..8), 0 (pad 9..11)
//   conv : x -> wlog partial sums (atomicAdd) + fused gap sums (atomicAdd)
//          4-output-row tile per wave, weights in registers
//   chnet: gap -> ch (8,256)
//   final: softmax over taps * reflect-padded patches -> out

#define EPS 1e-5f
#define CH_SPLIT 4
#define CH_PER_WAVE 16

__global__ __launch_bounds__(256) void prep_kernel(
    const float* __restrict__ wconv, const float* __restrict__ gamma,
    const float* __restrict__ beta, const float* __restrict__ mean,
    const float* __restrict__ var, float* __restrict__ wt,
    float* __restrict__ bias, float* __restrict__ gap) {
  const int c = threadIdx.x;  // 0..255
  #pragma unroll
  for (int t = 0; t < 9; ++t) {
    float sc = gamma[t] * rsqrtf(var[t] + EPS);
    #pragma unroll
    for (int p = 0; p < 9; ++p)
      wt[c * 84 + t * 9 + p] = wconv[((size_t)t * 256 + c) * 9 + p] * sc;
  }
  wt[c * 84 + 81] = 0.f;
  wt[c * 84 + 82] = 0.f;
  wt[c * 84 + 83] = 0.f;
  if (c < 9) bias[c] = beta[c] - mean[c] * gamma[c] * rsqrtf(var[c] + EPS);
  else if (c < 16) bias[c] = 0.f;
  #pragma unroll
  for (int k = 0; k < 8; ++k) gap[k * 256 + c] = 0.f;  // zero 2048 gap slots
}

// wlog[pos*12 + t] = bias[t] for t<9 else 0.  393216 floats total.
__global__ __launch_bounds__(256) void init_wlog_kernel(
    const float* __restrict__ bias, float* __restrict__ wlog) {
  const int idx = blockIdx.x * 256 + threadIdx.x;
  const int t = idx % 12;
  wlog[idx] = (t < 9) ? bias[t] : 0.f;
}

// Block 256 = 4 waves. Wave wv: channels [(z*4+wv)*16, +16), output rows
// i0..i0+3 of batch b. Lanes = 64 output cols. Per channel: 9 coalesced
// float2 row loads + shfl_up for left taps, 324 FMAs vs register weights.
// Rows r=1..8 (h=2*i0..2*i0+7) tile the image once -> fused gap sum.
__global__ __launch_bounds__(256, 2) void conv_kernel(
    const float* __restrict__ x, const float* __restrict__ wt,
    float* __restrict__ wlog, float* __restrict__ gap) {
  const int j = threadIdx.x & 63;
  const int wv = threadIdx.x >> 6;
  const int i0 = blockIdx.x * 4;
  const int b = blockIdx.y;
  const int z = blockIdx.z;
  const int cbase = __builtin_amdgcn_readfirstlane((z * 4 + wv) * CH_PER_WAVE);

  float acc[4][9];
  #pragma unroll
  for (int ri = 0; ri < 4; ++ri)
    #pragma unroll
    for (int t = 0; t < 9; ++t) acc[ri][t] = 0.f;

  const float* xb = x + ((size_t)b * 256 + cbase) * 16384;
  const float4* wq = (const float4*)(wt + (size_t)cbase * 84);
  const int h0 = 2 * i0 - 1;

  for (int c = 0; c < CH_PER_WAVE; ++c, xb += 16384, wq += 21) {
    float2 v[9];
    #pragma unroll
    for (int r = 0; r < 9; ++r) {
      const int hh = h0 + r;  // block-uniform; only -1 possible OOB
      if ((unsigned)hh < 128u)
        v[r] = *(const float2*)(xb + hh * 128 + 2 * j);
      else
        v[r] = make_float2(0.f, 0.f);
    }
    float lf[9];
    #pragma unroll
    for (int r = 0; r < 9; ++r) {
      float t = __shfl_up(v[r].y, 1, 64);
      lf[r] = (j == 0) ? 0.f : t;  // zero-pad col -1 (conv pad)
    }
    // fused gap: rows r=1..8 owned exactly once across the grid
    float gs = 0.f;
    #pragma unroll
    for (int r = 1; r < 9; ++r) gs += v[r].x + v[r].y;
    #pragma unroll
    for (int off = 32; off; off >>= 1) gs += __shfl_xor(gs, off, 64);
    if (j == 0) atomicAdd(&gap[b * 256 + cbase + c], gs);

    float4 w4[21];
    #pragma unroll
    for (int q = 0; q < 21; ++q) w4[q] = wq[q];
    const float* w = (const float*)w4;

    #pragma unroll
    for (int ri = 0; ri < 4; ++ri) {
      #pragma unroll
      for (int ki = 0; ki < 3; ++ki) {
        const int r = 2 * ri + ki;
        const float x0 = lf[r], x1 = v[r].x, x2 = v[r].y;
        #pragma unroll
        for (int t = 0; t < 9; ++t) {
          float a = acc[ri][t];
          a = fmaf(x0, w[t * 9 + ki * 3 + 0], a);
          a = fmaf(x1, w[t * 9 + ki * 3 + 1], a);
          a = fmaf(x2, w[t * 9 + ki * 3 + 2], a);
          acc[ri][t] = a;
        }
      }
    }
  }

  __shared__ float red[4][64][9];
  #pragma unroll
  for (int ri = 0; ri < 4; ++ri) {
    __syncthreads();
    #pragma unroll
    for (int t = 0; t < 9; ++t) red[wv][j][t] = acc[ri][t];
    __syncthreads();
    const size_t rowpos = ((size_t)b * 64 + (i0 + ri)) * 64;
    for (int idx = threadIdx.x; idx < 576; idx += 256) {
      const int jj = idx / 9, tt = idx - jj * 9;
      float s =
          red[0][jj][tt] + red[1][jj][tt] + red[2][jj][tt] + red[3][jj][tt];
      atomicAdd(&wlog[(rowpos + jj) * 12 + tt], s);
    }
  }
}

__global__ __launch_bounds__(256) void chnet_kernel(
    const float* __restrict__ gap, const float* __restrict__ w1,
    const float* __restrict__ w2, float* __restrict__ ch) {
  const int b = blockIdx.x;  // 0..7
  __shared__ float g[256];
  __shared__ float h[64];
  const int t = threadIdx.x;
  g[t] = gap[b * 256 + t] * (1.f / 16384.f);
  __syncthreads();
  if (t < 64) {
    float s = 0.f;
    const float* w = w1 + t * 256;
    for (int c = 0; c < 256; ++c) s += g[c] * w[c];
    h[t] = fmaxf(s, 0.f);
  }
  __syncthreads();
  float s = 0.f;
  const float* w = w2 + t * 64;
  #pragma unroll 4
  for (int j = 0; j < 64; ++j) s += h[j] * w[j];
  ch[b * 256 + t] = s;
}

__global__ __launch_bounds__(256) void final_kernel(
    const float* __restrict__ x, const float* __restrict__ wlog,
    const float* __restrict__ ch, float* __restrict__ out) {
  const int j = threadIdx.x & 63;
  const int il = threadIdx.x >> 6;  // 0..3
  const int i = blockIdx.x * 4 + il;
  const int c = blockIdx.y;
  const int b = blockIdx.z;
  const float chv = ch[b * 256 + c];

  const size_t pos = ((size_t)b * 64 + i) * 64 + j;
  const float4* wp = (const float4*)(wlog + pos * 12);
  float4 wa = wp[0], wb = wp[1], wcv = wp[2];
  float lg[9] = {wa.x, wa.y, wa.z, wa.w, wb.x, wb.y, wb.z, wb.w, wcv.x};

  float m = -3.4e38f;
  #pragma unroll
  for (int t = 0; t < 9; ++t) {
    lg[t] *= chv;
    m = fmaxf(m, lg[t]);
  }
  float e[9], s = 0.f;
  #pragma unroll
  for (int t = 0; t < 9; ++t) {
    e[t] = __expf(lg[t] - m);
    s += e[t];
  }
  const float inv = 1.f / s;

  const float* xp = x + ((size_t)b * 256 + c) * 16384;
  float acc = 0.f;
  #pragma unroll
  for (int ki = 0; ki < 3; ++ki) {
    int hh = 2 * i - 1 + ki;     // -1..127; only -1 needs reflect
    hh = hh < 0 ? -hh : hh;
    float2 v = *(const float2*)(xp + hh * 128 + 2 * j);
    float left = __shfl_up(v.y, 1, 64);  // lane0: own v.y = col1 = reflect(-1)
    acc += e[ki * 3 + 0] * left + e[ki * 3 + 1] * v.x + e[ki * 3 + 2] * v.y;
  }
  out[(size_t)(b * 256 + c) * 4096 + i * 64 + j] = acc * inv;
}

extern "C" void kernel_launch(void* const* d_in, const int* in_sizes, int n_in,
                              void* d_out, int out_size, void* d_ws,
                              size_t ws_size, hipStream_t stream) {
  const float* x = (const float*)d_in[0];
  const float* w_conv = (const float*)d_in[1];
  const float* bn_gamma = (const float*)d_in[2];
  const float* bn_beta = (const float*)d_in[3];
  const float* bn_mean = (const float*)d_in[4];
  const float* bn_var = (const float*)d_in[5];
  const float* ch_w1 = (const float*)d_in[6];
  const float* ch_w2 = (const float*)d_in[7];
  float* out = (float*)d_out;

  float* wsf = (float*)d_ws;
  float* gap = wsf;           // 2048
  float* ch = wsf + 2048;     // 2048
  float* bias = wsf + 4096;   // 16
  float* wt = wsf + 4112;     // 256*84 = 21504
  float* wlog = wsf + 25616;  // 8*64*64*12 = 393216

  prep_kernel<<<1, 256, 0, stream>>>(w_conv, bn_gamma, bn_beta, bn_mean,
                                     bn_var, wt, bias, gap);
  init_wlog_kernel<<<1536, 256, 0, stream>>>(bias, wlog);
  conv_kernel<<<dim3(16, 8, CH_SPLIT), 256, 0, stream>>>(x, wt, wlog, gap);
  chnet_kernel<<<8, 256, 0, stream>>>(gap, ch_w1, ch_w2, ch);
  final_kernel<<<dim3(16, 256, 8), 256, 0, stream>>>(x, wlog, ch, out);
}

// Round 4
// 86.115 us; speedup vs baseline: 2.3912x; 1.0945x over previous
//
#include <hip/hip_runtime.h>
#include <hip/hip_bf16.h>

// AdaDConv: B=8, C=256, H=W=128, K=3, S=2 -> oh=ow=64, k2=9
//   prep_init : fold BN into conv weights -> wt[c][3][28] chunks; zero gap;
//               wlog[pos][12] <- bias (taps 0..8), 0 (pad 9..11)
//   conv      : x -> wlog partial sums (atomicAdd) + fused gap sums
//               4-output-row tile/wave, 8 ch/wave, weights in 28-reg chunks
//   chnet     : gap -> ch (8,256)
//   final     : c-loop in block; wlog in regs; softmax * reflect patches -> out

#define EPS 1e-5f
#define CH_SPLIT 8
#define CH_PER_WAVE 8

// grid 1537: blocks 0..1535 init wlog; block 1536 does weights + gap zero.
__global__ __launch_bounds__(256) void prep_init_kernel(
    const float* __restrict__ wconv, const float* __restrict__ gamma,
    const float* __restrict__ beta, const float* __restrict__ mean,
    const float* __restrict__ var, float* __restrict__ wt,
    float* __restrict__ gap, float* __restrict__ wlog) {
  const int blk = blockIdx.x;
  if (blk < 1536) {
    float biasv[9];
    #pragma unroll
    for (int t = 0; t < 9; ++t)
      biasv[t] = beta[t] - mean[t] * gamma[t] * rsqrtf(var[t] + EPS);
    const int idx = blk * 256 + threadIdx.x;
    const int t = idx % 12;
    wlog[idx] = (t < 9) ? biasv[t] : 0.f;
  } else {
    const int c = threadIdx.x;  // 0..255
    // layout: wt[c*84 + ki*28 + t*3 + kj], slot 27 of each chunk = 0
    #pragma unroll
    for (int t = 0; t < 9; ++t) {
      float sc = gamma[t] * rsqrtf(var[t] + EPS);
      #pragma unroll
      for (int ki = 0; ki < 3; ++ki)
        #pragma unroll
        for (int kj = 0; kj < 3; ++kj)
          wt[c * 84 + ki * 28 + t * 3 + kj] =
              wconv[((size_t)t * 256 + c) * 9 + ki * 3 + kj] * sc;
    }
    #pragma unroll
    for (int ki = 0; ki < 3; ++ki) wt[c * 84 + ki * 28 + 27] = 0.f;
    #pragma unroll
    for (int k = 0; k < 8; ++k) gap[k * 256 + c] = 0.f;
  }
}

// Block 256 = 4 waves. Wave wv: channels [(z*4+wv)*8, +8), output rows
// i0..i0+3 of batch b. Lanes = 64 output cols. Per channel: 9 coalesced
// float2 row loads + shfl_up left taps; 324 FMAs vs 28-reg weight chunks.
// Rows r=1..8 (h=2*i0..2*i0+7) tile the image once -> fused gap sum.
__global__ __launch_bounds__(256, 4) void conv_kernel(
    const float* __restrict__ x, const float* __restrict__ wt,
    float* __restrict__ wlog, float* __restrict__ gap) {
  const int j = threadIdx.x & 63;
  const int wv = threadIdx.x >> 6;
  const int i0 = blockIdx.x * 4;
  const int b = blockIdx.y;
  const int z = blockIdx.z;
  const int cbase = __builtin_amdgcn_readfirstlane((z * 4 + wv) * CH_PER_WAVE);

  float acc[4][9];
  #pragma unroll
  for (int ri = 0; ri < 4; ++ri)
    #pragma unroll
    for (int t = 0; t < 9; ++t) acc[ri][t] = 0.f;

  const float* xb = x + ((size_t)b * 256 + cbase) * 16384;
  const float* wcb = wt + (size_t)cbase * 84;
  const int h0 = 2 * i0 - 1;

  for (int c = 0; c < CH_PER_WAVE; ++c, xb += 16384, wcb += 84) {
    float2 v[9];
    #pragma unroll
    for (int r = 0; r < 9; ++r) {
      const int hh = h0 + r;  // block-uniform; only -1 possible OOB
      if ((unsigned)hh < 128u)
        v[r] = *(const float2*)(xb + hh * 128 + 2 * j);
      else
        v[r] = make_float2(0.f, 0.f);
    }
    float lf[9];
    #pragma unroll
    for (int r = 0; r < 9; ++r) {
      float t = __shfl_up(v[r].y, 1, 64);
      lf[r] = (j == 0) ? 0.f : t;  // zero-pad col -1 (conv pad)
    }
    // fused gap: rows r=1..8 owned exactly once across the grid
    float gs = 0.f;
    #pragma unroll
    for (int r = 1; r < 9; ++r) gs += v[r].x + v[r].y;
    #pragma unroll
    for (int off = 32; off; off >>= 1) gs += __shfl_xor(gs, off, 64);
    if (j == 0) atomicAdd(&gap[b * 256 + cbase + c], gs);

    #pragma unroll
    for (int ki = 0; ki < 3; ++ki) {
      float4 wk[7];
      const float4* wq = (const float4*)(wcb + ki * 28);
      #pragma unroll
      for (int q = 0; q < 7; ++q) wk[q] = wq[q];
      const float* w = (const float*)wk;  // w[t*3 + kj]
      #pragma unroll
      for (int ri = 0; ri < 4; ++ri) {
        const int r = 2 * ri + ki;
        const float x0 = lf[r], x1 = v[r].x, x2 = v[r].y;
        #pragma unroll
        for (int t = 0; t < 9; ++t) {
          float a = acc[ri][t];
          a = fmaf(x0, w[t * 3 + 0], a);
          a = fmaf(x1, w[t * 3 + 1], a);
          a = fmaf(x2, w[t * 3 + 2], a);
          acc[ri][t] = a;
        }
      }
    }
  }

  __shared__ float red[4][64][9];
  #pragma unroll
  for (int ri = 0; ri < 4; ++ri) {
    __syncthreads();
    #pragma unroll
    for (int t = 0; t < 9; ++t) red[wv][j][t] = acc[ri][t];
    __syncthreads();
    const size_t rowpos = ((size_t)b * 64 + (i0 + ri)) * 64;
    for (int idx = threadIdx.x; idx < 576; idx += 256) {
      const int jj = idx / 9, tt = idx - jj * 9;
      float s =
          red[0][jj][tt] + red[1][jj][tt] + red[2][jj][tt] + red[3][jj][tt];
      atomicAdd(&wlog[(rowpos + jj) * 12 + tt], s);
    }
  }
}

__global__ __launch_bounds__(256) void chnet_kernel(
    const float* __restrict__ gap, const float* __restrict__ w1,
    const float* __restrict__ w2, float* __restrict__ ch) {
  const int b = blockIdx.x;  // 0..7
  __shared__ float g[256];
  __shared__ float h[64];
  const int t = threadIdx.x;
  g[t] = gap[b * 256 + t] * (1.f / 16384.f);
  __syncthreads();
  if (t < 64) {
    float s = 0.f;
    const float* w = w1 + t * 256;
    for (int c = 0; c < 256; ++c) s += g[c] * w[c];
    h[t] = fmaxf(s, 0.f);
  }
  __syncthreads();
  float s = 0.f;
  const float* w = w2 + t * 64;
  #pragma unroll 4
  for (int j = 0; j < 64; ++j) s += h[j] * w[j];
  ch[b * 256 + t] = s;
}

// Block: (j 0..63, il 0..3) pixels of 4 output rows; loop 32 channels.
// wlog for the pixel lives in 9 registers across the whole c-loop.
__global__ __launch_bounds__(256) void final_kernel(
    const float* __restrict__ x, const float* __restrict__ wlog,
    const float* __restrict__ ch, float* __restrict__ out) {
  const int j = threadIdx.x & 63;
  const int il = threadIdx.x >> 6;  // 0..3
  const int i = blockIdx.x * 4 + il;
  const int b = blockIdx.y;
  const int c0 = blockIdx.z * 32;

  const size_t pos = ((size_t)b * 64 + i) * 64 + j;
  const float4* wp = (const float4*)(wlog + pos * 12);
  float4 wa = wp[0], wb = wp[1], wcv = wp[2];
  const float wl[9] = {wa.x, wa.y, wa.z, wa.w, wb.x, wb.y, wb.z, wb.w, wcv.x};

  const float* chp = ch + b * 256 + c0;
  const float* xp0 = x + ((size_t)b * 256 + c0) * 16384;
  float* op = out + ((size_t)b * 256 + c0) * 4096 + i * 64 + j;

  for (int c = 0; c < 32; ++c) {
    const float chv = chp[c];
    const float* xp = xp0 + (size_t)c * 16384;

    float2 v0, v1, v2;
    {
      int hh = 2 * i - 1;
      hh = hh < 0 ? -hh : hh;
      v0 = *(const float2*)(xp + hh * 128 + 2 * j);
      v1 = *(const float2*)(xp + (2 * i) * 128 + 2 * j);
      v2 = *(const float2*)(xp + (2 * i + 1) * 128 + 2 * j);
    }

    float lg[9], m = -3.4e38f;
    #pragma unroll
    for (int t = 0; t < 9; ++t) {
      lg[t] = wl[t] * chv;
      m = fmaxf(m, lg[t]);
    }
    float e[9], s = 0.f;
    #pragma unroll
    for (int t = 0; t < 9; ++t) {
      e[t] = __expf(lg[t] - m);
      s += e[t];
    }
    const float inv = 1.f / s;

    // lane0 shfl_up returns own v.y = col1 = reflect(col -1)
    float l0 = __shfl_up(v0.y, 1, 64);
    float l1 = __shfl_up(v1.y, 1, 64);
    float l2 = __shfl_up(v2.y, 1, 64);
    float acc = e[0] * l0 + e[1] * v0.x + e[2] * v0.y;
    acc += e[3] * l1 + e[4] * v1.x + e[5] * v1.y;
    acc += e[6] * l2 + e[7] * v2.x + e[8] * v2.y;

    op[(size_t)c * 4096] = acc * inv;
  }
}

extern "C" void kernel_launch(void* const* d_in, const int* in_sizes, int n_in,
                              void* d_out, int out_size, void* d_ws,
                              size_t ws_size, hipStream_t stream) {
  const float* x = (const float*)d_in[0];
  const float* w_conv = (const float*)d_in[1];
  const float* bn_gamma = (const float*)d_in[2];
  const float* bn_beta = (const float*)d_in[3];
  const float* bn_mean = (const float*)d_in[4];
  const float* bn_var = (const float*)d_in[5];
  const float* ch_w1 = (const float*)d_in[6];
  const float* ch_w2 = (const float*)d_in[7];
  float* out = (float*)d_out;

  float* wsf = (float*)d_ws;
  float* gap = wsf;           // 2048
  float* ch = wsf + 2048;     // 2048
  float* wt = wsf + 4096;     // 256*84 = 21504
  float* wlog = wsf + 25600;  // 8*64*64*12 = 393216 (16B-aligned)

  prep_init_kernel<<<1537, 256, 0, stream>>>(w_conv, bn_gamma, bn_beta,
                                             bn_mean, bn_var, wt, gap, wlog);
  conv_kernel<<<dim3(16, 8, CH_SPLIT), 256, 0, stream>>>(x, wt, wlog, gap);
  chnet_kernel<<<8, 256, 0, stream>>>(gap, ch_w1, ch_w2, ch);
  final_kernel<<<dim3(16, 8, 8), 256, 0, stream>>>(x, wlog, ch, out);
}

// Round 5
// 79.325 us; speedup vs baseline: 2.5959x; 1.0856x over previous
//
#include <hip/hip_runtime.h>
#include <hip/hip_bf16.h>

// AdaDConv: B=8, C=256, H=W=128, K=3, S=2 -> oh=ow=64, k2=9
//   prep   : fold BN into conv weights -> wt[c][3][28] chunks; bias[16]; gap=0
//   conv   : x -> wlogp[z] partials (plain stores, no atomics) + fused gap
//            4-output-row tile/wave, 8 ch/wave, weights staged in LDS
//   reduce : wlog = sum_z wlogp[z] + bias   (+ chnet in blocks 384..391)
//   final  : c-loop in block; wlog in regs; softmax * reflect patches -> out

#define EPS 1e-5f
#define CH_SPLIT 8
#define CH_PER_WAVE 8
#define WLOG_N 393216  // 8*64*64*12

__global__ __launch_bounds__(256) void prep_kernel(
    const float* __restrict__ wconv, const float* __restrict__ gamma,
    const float* __restrict__ beta, const float* __restrict__ mean,
    const float* __restrict__ var, float* __restrict__ wt,
    float* __restrict__ bias, float* __restrict__ gap) {
  const int c = threadIdx.x;  // 0..255
  // layout: wt[c*84 + ki*28 + t*3 + kj], slot 27 of each chunk = 0
  #pragma unroll
  for (int t = 0; t < 9; ++t) {
    float sc = gamma[t] * rsqrtf(var[t] + EPS);
    #pragma unroll
    for (int ki = 0; ki < 3; ++ki)
      #pragma unroll
      for (int kj = 0; kj < 3; ++kj)
        wt[c * 84 + ki * 28 + t * 3 + kj] =
            wconv[((size_t)t * 256 + c) * 9 + ki * 3 + kj] * sc;
  }
  #pragma unroll
  for (int ki = 0; ki < 3; ++ki) wt[c * 84 + ki * 28 + 27] = 0.f;
  #pragma unroll
  for (int k = 0; k < 8; ++k) gap[k * 256 + c] = 0.f;
  if (c < 9) bias[c] = beta[c] - mean[c] * gamma[c] * rsqrtf(var[c] + EPS);
  else if (c < 16) bias[c] = 0.f;
}

// Block 256 = 4 waves; block covers channels [z*32, z*32+32) (wave wv owns
// 8), output rows i0..i0+3 of batch b, lanes = 64 output cols.
// Weights staged once into LDS; per channel: 9 coalesced float2 row loads +
// shfl_up left taps; 324 FMAs. Rows r=1..8 tile the image once -> gap sum.
__global__ __launch_bounds__(256, 4) void conv_kernel(
    const float* __restrict__ x, const float* __restrict__ wt,
    float* __restrict__ wlogp, float* __restrict__ gap) {
  const int j = threadIdx.x & 63;
  const int wv = threadIdx.x >> 6;
  const int i0 = blockIdx.x * 4;
  const int b = blockIdx.y;
  const int z = blockIdx.z;

  __shared__ float sw[2688];  // 32 ch * 84
  __shared__ float red[4][64][9];

  {  // cooperative weight stage: channels z*32 .. z*32+31
    const float4* src = (const float4*)(wt + (size_t)z * 32 * 84);
    float4* dst = (float4*)sw;
    #pragma unroll
    for (int k = 0; k < 3; ++k) {
      int idx = k * 256 + threadIdx.x;
      if (idx < 672) dst[idx] = src[idx];
    }
  }
  __syncthreads();

  float acc[4][9];
  #pragma unroll
  for (int ri = 0; ri < 4; ++ri)
    #pragma unroll
    for (int t = 0; t < 9; ++t) acc[ri][t] = 0.f;

  const int cbase = z * 32 + wv * CH_PER_WAVE;
  const float* xb = x + ((size_t)b * 256 + cbase) * 16384;
  const float* swb = sw + (wv * CH_PER_WAVE) * 84;
  const int h0 = 2 * i0 - 1;

  for (int c = 0; c < CH_PER_WAVE; ++c, xb += 16384) {
    float2 v[9];
    #pragma unroll
    for (int r = 0; r < 9; ++r) {
      const int hh = h0 + r;  // block-uniform; only -1 possible OOB
      if ((unsigned)hh < 128u)
        v[r] = *(const float2*)(xb + hh * 128 + 2 * j);
      else
        v[r] = make_float2(0.f, 0.f);
    }
    float lf[9];
    #pragma unroll
    for (int r = 0; r < 9; ++r) {
      float t = __shfl_up(v[r].y, 1, 64);
      lf[r] = (j == 0) ? 0.f : t;  // zero-pad col -1 (conv pad)
    }
    // fused gap: rows r=1..8 owned exactly once across the grid
    float gs = 0.f;
    #pragma unroll
    for (int r = 1; r < 9; ++r) gs += v[r].x + v[r].y;
    #pragma unroll
    for (int off = 32; off; off >>= 1) gs += __shfl_xor(gs, off, 64);
    if (j == 0) atomicAdd(&gap[b * 256 + cbase + c], gs);

    const float* wcb = swb + c * 84;
    #pragma unroll
    for (int ki = 0; ki < 3; ++ki) {
      float4 wk[7];
      const float4* wq = (const float4*)(wcb + ki * 28);
      #pragma unroll
      for (int q = 0; q < 7; ++q) wk[q] = wq[q];
      const float* w = (const float*)wk;  // w[t*3 + kj]
      #pragma unroll
      for (int ri = 0; ri < 4; ++ri) {
        const int r = 2 * ri + ki;
        const float x0 = lf[r], x1 = v[r].x, x2 = v[r].y;
        #pragma unroll
        for (int t = 0; t < 9; ++t) {
          float a = acc[ri][t];
          a = fmaf(x0, w[t * 3 + 0], a);
          a = fmaf(x1, w[t * 3 + 1], a);
          a = fmaf(x2, w[t * 3 + 2], a);
          acc[ri][t] = a;
        }
      }
    }
  }

  float* wzp = wlogp + (size_t)z * WLOG_N;
  #pragma unroll
  for (int ri = 0; ri < 4; ++ri) {
    __syncthreads();
    #pragma unroll
    for (int t = 0; t < 9; ++t) red[wv][j][t] = acc[ri][t];
    __syncthreads();
    const size_t rowpos = ((size_t)b * 64 + (i0 + ri)) * 64;
    float* wp = wzp + rowpos * 12;
    for (int idx = threadIdx.x; idx < 768; idx += 256) {
      const int jj = idx / 12, tt = idx - jj * 12;
      float s = 0.f;
      if (tt < 9)
        s = red[0][jj][tt] + red[1][jj][tt] + red[2][jj][tt] + red[3][jj][tt];
      wp[idx] = s;  // coalesced; pad slots get 0
    }
  }
}

// blocks 0..383: wlog[i] = sum_z wlogp[z][i] + bias[i%12]  (float4/thread)
// blocks 384..391: chnet for b = blk-384
__global__ __launch_bounds__(256) void reduce_chnet_kernel(
    const float* __restrict__ wlogp, const float* __restrict__ bias,
    float* __restrict__ wlog, const float* __restrict__ gap,
    const float* __restrict__ w1, const float* __restrict__ w2,
    float* __restrict__ ch) {
  __shared__ float g[256];
  __shared__ float h[64];
  const int blk = blockIdx.x;
  if (blk < 384) {
    const int i4 = blk * 256 + threadIdx.x;  // float4 index
    float4 s = make_float4(0.f, 0.f, 0.f, 0.f);
    #pragma unroll
    for (int zz = 0; zz < 8; ++zz) {
      float4 p = *(const float4*)(wlogp + (size_t)zz * WLOG_N + (size_t)i4 * 4);
      s.x += p.x; s.y += p.y; s.z += p.z; s.w += p.w;
    }
    const int base = i4 * 4;
    s.x += bias[(base + 0) % 12];
    s.y += bias[(base + 1) % 12];
    s.z += bias[(base + 2) % 12];
    s.w += bias[(base + 3) % 12];
    *(float4*)(wlog + base) = s;
  } else {
    const int b = blk - 384;
    const int t = threadIdx.x;
    g[t] = gap[b * 256 + t] * (1.f / 16384.f);
    __syncthreads();
    if (t < 64) {
      float s = 0.f;
      const float* w = w1 + t * 256;
      for (int c = 0; c < 256; ++c) s += g[c] * w[c];
      h[t] = fmaxf(s, 0.f);
    }
    __syncthreads();
    float s = 0.f;
    const float* w = w2 + t * 64;
    #pragma unroll 4
    for (int jj = 0; jj < 64; ++jj) s += h[jj] * w[jj];
    ch[b * 256 + t] = s;
  }
}

// Block: (j 0..63, il 0..3) pixels of 4 output rows; loop 16 channels.
// wlog for the pixel lives in 9 registers across the whole c-loop.
__global__ __launch_bounds__(256) void final_kernel(
    const float* __restrict__ x, const float* __restrict__ wlog,
    const float* __restrict__ ch, float* __restrict__ out) {
  const int j = threadIdx.x & 63;
  const int il = threadIdx.x >> 6;  // 0..3
  const int i = blockIdx.x * 4 + il;
  const int b = blockIdx.y;
  const int c0 = blockIdx.z * 16;

  const size_t pos = ((size_t)b * 64 + i) * 64 + j;
  const float4* wp = (const float4*)(wlog + pos * 12);
  float4 wa = wp[0], wb = wp[1], wcv = wp[2];
  const float wl[9] = {wa.x, wa.y, wa.z, wa.w, wb.x, wb.y, wb.z, wb.w, wcv.x};

  const float* chp = ch + b * 256 + c0;
  const float* xp0 = x + ((size_t)b * 256 + c0) * 16384;
  float* op = out + ((size_t)b * 256 + c0) * 4096 + i * 64 + j;

  for (int c = 0; c < 16; ++c) {
    const float chv = chp[c];
    const float* xp = xp0 + (size_t)c * 16384;

    float2 v0, v1, v2;
    {
      int hh = 2 * i - 1;
      hh = hh < 0 ? -hh : hh;
      v0 = *(const float2*)(xp + hh * 128 + 2 * j);
      v1 = *(const float2*)(xp + (2 * i) * 128 + 2 * j);
      v2 = *(const float2*)(xp + (2 * i + 1) * 128 + 2 * j);
    }

    float lg[9], m = -3.4e38f;
    #pragma unroll
    for (int t = 0; t < 9; ++t) {
      lg[t] = wl[t] * chv;
      m = fmaxf(m, lg[t]);
    }
    float e[9], s = 0.f;
    #pragma unroll
    for (int t = 0; t < 9; ++t) {
      e[t] = __expf(lg[t] - m);
      s += e[t];
    }
    const float inv = 1.f / s;

    // lane0 shfl_up returns own v.y = col1 = reflect(col -1)
    float l0 = __shfl_up(v0.y, 1, 64);
    float l1 = __shfl_up(v1.y, 1, 64);
    float l2 = __shfl_up(v2.y, 1, 64);
    float acc = e[0] * l0 + e[1] * v0.x + e[2] * v0.y;
    acc += e[3] * l1 + e[4] * v1.x + e[5] * v1.y;
    acc += e[6] * l2 + e[7] * v2.x + e[8] * v2.y;

    op[(size_t)c * 4096] = acc * inv;
  }
}

extern "C" void kernel_launch(void* const* d_in, const int* in_sizes, int n_in,
                              void* d_out, int out_size, void* d_ws,
                              size_t ws_size, hipStream_t stream) {
  const float* x = (const float*)d_in[0];
  const float* w_conv = (const float*)d_in[1];
  const float* bn_gamma = (const float*)d_in[2];
  const float* bn_beta = (const float*)d_in[3];
  const float* bn_mean = (const float*)d_in[4];
  const float* bn_var = (const float*)d_in[5];
  const float* ch_w1 = (const float*)d_in[6];
  const float* ch_w2 = (const float*)d_in[7];
  float* out = (float*)d_out;

  float* wsf = (float*)d_ws;
  float* gap = wsf;            // 2048
  float* ch = wsf + 2048;      // 2048
  float* bias = wsf + 4096;    // 16
  float* wt = wsf + 4112;      // 256*84 = 21504
  float* wlog = wsf + 25616;   // 393216
  float* wlogp = wsf + 418832; // 8*393216 = 3145728

  prep_kernel<<<1, 256, 0, stream>>>(w_conv, bn_gamma, bn_beta, bn_mean,
                                     bn_var, wt, bias, gap);
  conv_kernel<<<dim3(16, 8, CH_SPLIT), 256, 0, stream>>>(x, wt, wlogp, gap);
  reduce_chnet_kernel<<<392, 256, 0, stream>>>(wlogp, bias, wlog, gap, ch_w1,
                                               ch_w2, ch);
  final_kernel<<<dim3(16, 8, 16), 256, 0, stream>>>(x, wlog, ch, out);
}